// Round 1
// baseline (1436.269 us; speedup 1.0000x reference)
//
#include <hip/hip_runtime.h>
#include <math.h>

#define N_NODES_C 50000
#define E_C       800000
#define ATT_IN_C  176
#define ATT_HID_C 144

// workspace layout (bytes)
#define O_RAW  0L          // float[E]        3,200,000
#define O_DEG  3200000L    // int[N]            200,000
#define O_OFF  3400192L    // int[N+1]          200,004
#define O_CUR  3600384L    // int[N]            200,000
#define O_CSRE 3800576L    // int[E]          3,200,000
#define O_CSRS 7000576L    // int[E]          3,200,000
#define O_AGG  10200576L   // float[N*64]    12,800,000  -> total ~23.0 MB

__global__ __launch_bounds__(256) void k_zero_deg(int* __restrict__ deg) {
    int i = blockIdx.x * blockDim.x + threadIdx.x;
    if (i < N_NODES_C) deg[i] = 0;
}

__global__ __launch_bounds__(256) void k_deg(const int* __restrict__ ei, int* __restrict__ deg) {
    int e = blockIdx.x * blockDim.x + threadIdx.x;
    if (e < E_C) atomicAdd(&deg[ei[E_C + e]], 1);
}

__global__ __launch_bounds__(1024) void k_scan(const int* __restrict__ deg,
                                               int* __restrict__ offsets,
                                               int* __restrict__ cursor) {
    __shared__ int part[1024];
    int t = threadIdx.x;
    const int chunk = (N_NODES_C + 1023) / 1024;  // 49
    int lo = t * chunk; if (lo > N_NODES_C) lo = N_NODES_C;
    int hi = lo + chunk; if (hi > N_NODES_C) hi = N_NODES_C;
    int s = 0;
    for (int i = lo; i < hi; ++i) s += deg[i];
    part[t] = s;
    __syncthreads();
    for (int off = 1; off < 1024; off <<= 1) {
        int v = part[t];
        int add = (t >= off) ? part[t - off] : 0;
        __syncthreads();
        part[t] = v + add;
        __syncthreads();
    }
    int run = (t == 0) ? 0 : part[t - 1];
    for (int i = lo; i < hi; ++i) {
        offsets[i] = run;
        cursor[i]  = run;
        run += deg[i];
    }
    if (t == 1023) offsets[N_NODES_C] = part[1023];
}

__global__ __launch_bounds__(256) void k_fill(const int* __restrict__ ei,
                                              int* __restrict__ cursor,
                                              int* __restrict__ csr_e,
                                              int* __restrict__ csr_src) {
    int e = blockIdx.x * blockDim.x + threadIdx.x;
    if (e < E_C) {
        int dst  = ei[E_C + e];
        int slot = atomicAdd(&cursor[dst], 1);
        csr_e[slot]   = e;
        csr_src[slot] = ei[e];
    }
}

// ---- edge attention MLP: raw[e] = leaky_relu(w2 . relu(W1 . att_in + b1) + b2)
#define EPW 16  // edges per wave
__global__ __launch_bounds__(256) void k_scores(
    const float* __restrict__ x, const float* __restrict__ xs,
    const int* __restrict__ ei, const float* __restrict__ ef,
    const float* __restrict__ w1, const float* __restrict__ b1,
    const float* __restrict__ w2, const float* __restrict__ b2,
    float* __restrict__ raw)
{
    __shared__ float vbuf[4][EPW * ATT_IN_C];  // 45,056 B
    int tid  = threadIdx.x;
    int wave = tid >> 6, lane = tid & 63;
    long ebase = ((long)blockIdx.x * 4 + wave) * EPW;
    float* vb = vbuf[wave];

    // gather 16 edges x 44 float4-chunks = 704 items; each lane does 11
#pragma unroll
    for (int it = 0; it < 11; ++it) {
        int idx  = it * 64 + lane;           // < 704
        int eloc = idx / 44, c = idx % 44;
        long e  = ebase + eloc;
        long ec = e < (E_C - 1) ? e : (E_C - 1);
        int src = ei[ec], dst = ei[E_C + ec];
        const float* p;
        if (c < 16)      p = x  + (long)src * 64 + c * 4;
        else if (c < 32) p = x  + (long)dst * 64 + (c - 16) * 4;
        else if (c < 36) p = xs + (long)src * 16 + (c - 32) * 4;
        else if (c < 40) p = xs + (long)dst * 16 + (c - 36) * 4;
        else             p = ef + ec * 16 + (c - 40) * 4;
        float4 val = *(const float4*)p;
        *(float4*)&vb[eloc * ATT_IN_C + c * 4] = val;
    }
    __syncthreads();

    // per lane: hidden rows j0=lane, j1=lane+64, j2=min(lane+128,143)
    int j0 = lane, j1 = lane + 64;
    int j2 = (lane + 128 < ATT_HID_C) ? (lane + 128) : (ATT_HID_C - 1);
    const float* wr0 = w1 + (long)j0 * ATT_IN_C;
    const float* wr1 = w1 + (long)j1 * ATT_IN_C;
    const float* wr2 = w1 + (long)j2 * ATT_IN_C;

    float acc0[EPW], acc1[EPW], acc2[EPW];
#pragma unroll
    for (int e = 0; e < EPW; ++e) { acc0[e] = 0.f; acc1[e] = 0.f; acc2[e] = 0.f; }

    for (int c = 0; c < 44; ++c) {
        float4 a  = *(const float4*)(wr0 + c * 4);
        float4 b  = *(const float4*)(wr1 + c * 4);
        float4 cc = *(const float4*)(wr2 + c * 4);
#pragma unroll
        for (int e = 0; e < EPW; ++e) {
            float4 v = *(float4*)&vb[e * ATT_IN_C + c * 4];
            acc0[e] += a.x * v.x + a.y * v.y + a.z * v.z + a.w * v.w;
            acc1[e] += b.x * v.x + b.y * v.y + b.z * v.z + b.w * v.w;
            acc2[e] += cc.x * v.x + cc.y * v.y + cc.z * v.z + cc.w * v.w;
        }
    }

    float b1v0 = b1[j0], b1v1 = b1[j1], b1v2 = b1[j2];
    float w2v0 = w2[j0], w2v1 = w2[j1];
    float w2v2 = (lane + 128 < ATT_HID_C) ? w2[lane + 128] : 0.f;
    float b2v  = b2[0];

#pragma unroll
    for (int e = 0; e < EPW; ++e) {
        float h0 = fmaxf(acc0[e] + b1v0, 0.f);
        float h1 = fmaxf(acc1[e] + b1v1, 0.f);
        float h2 = fmaxf(acc2[e] + b1v2, 0.f);
        float part = h0 * w2v0 + h1 * w2v1 + h2 * w2v2;
#pragma unroll
        for (int off = 32; off > 0; off >>= 1) part += __shfl_xor(part, off, 64);
        if (lane == 0) {
            float r = part + b2v;
            r = (r >= 0.f) ? r : 0.01f * r;
            long eo = ebase + e;
            if (eo < E_C) raw[eo] = r;
        }
    }
}

// ---- per-node segment softmax + weighted gather (exact semantics, no float atomics)
__global__ __launch_bounds__(256) void k_agg(
    const float* __restrict__ x, const int* __restrict__ offsets,
    const int* __restrict__ csr_e, const int* __restrict__ csr_src,
    const float* __restrict__ raw, float* __restrict__ agg)
{
    int tid = threadIdx.x;
    int wave = tid >> 6, lane = tid & 63;
    int v = blockIdx.x * 4 + wave;
    if (v >= N_NODES_C) return;
    int s0 = offsets[v], s1 = offsets[v + 1];

    float m = -INFINITY;
    for (int p = s0 + lane; p < s1; p += 64) m = fmaxf(m, raw[csr_e[p]]);
#pragma unroll
    for (int off = 32; off > 0; off >>= 1) m = fmaxf(m, __shfl_xor(m, off, 64));

    float acc = 0.f, sum = 0.f;
    for (int p = s0; p < s1; ++p) {
        int e   = csr_e[p];
        int src = csr_src[p];
        float w = expf(raw[e] - m);
        sum += w;
        acc += w * x[(long)src * 64 + lane];
    }
    agg[(long)v * 64 + lane] = acc / (sum + 1e-9f);
}

// ---- node update MLP: out = relu(W2 . relu(W1 . [x|agg] + b1) + b2)
#define NPW 16  // nodes per wave
__global__ __launch_bounds__(256) void k_upd(
    const float* __restrict__ x, const float* __restrict__ agg,
    const float* __restrict__ w1, const float* __restrict__ b1,
    const float* __restrict__ w2, const float* __restrict__ b2,
    float* __restrict__ out)
{
    __shared__ float inbuf[4][NPW * 128];
    __shared__ float ubuf[4][NPW * 128];
    int tid = threadIdx.x;
    int wave = tid >> 6, lane = tid & 63;
    long nbase = ((long)blockIdx.x * 4 + wave) * NPW;
    float* ib = inbuf[wave];
    float* ub = ubuf[wave];

    // gather [x | agg]: 16 nodes x 32 float4-chunks = 512 items; lane does 8
#pragma unroll
    for (int it = 0; it < 8; ++it) {
        int idx = it * 64 + lane;
        int nl = idx >> 5, c = idx & 31;
        long v  = nbase + nl;
        long vc = v < (N_NODES_C - 1) ? v : (N_NODES_C - 1);
        const float* p = (c < 16) ? (x + vc * 64 + c * 4)
                                  : (agg + vc * 64 + (c - 16) * 4);
        *(float4*)&ib[nl * 128 + c * 4] = *(const float4*)p;
    }
    __syncthreads();

    // hidden: j0 = lane, j1 = lane+64
    const float* wr0 = w1 + (long)lane * 128;
    const float* wr1 = w1 + (long)(lane + 64) * 128;
    float acc0[NPW], acc1[NPW];
#pragma unroll
    for (int n = 0; n < NPW; ++n) { acc0[n] = 0.f; acc1[n] = 0.f; }
    for (int c = 0; c < 32; ++c) {
        float4 a = *(const float4*)(wr0 + c * 4);
        float4 b = *(const float4*)(wr1 + c * 4);
#pragma unroll
        for (int n = 0; n < NPW; ++n) {
            float4 v = *(float4*)&ib[n * 128 + c * 4];
            acc0[n] += a.x * v.x + a.y * v.y + a.z * v.z + a.w * v.w;
            acc1[n] += b.x * v.x + b.y * v.y + b.z * v.z + b.w * v.w;
        }
    }
    float b10 = b1[lane], b11 = b1[lane + 64];
#pragma unroll
    for (int n = 0; n < NPW; ++n) {
        ub[n * 128 + lane]      = fmaxf(acc0[n] + b10, 0.f);
        ub[n * 128 + 64 + lane] = fmaxf(acc1[n] + b11, 0.f);
    }
    __syncthreads();

    // output: j = lane (64 outputs)
    const float* wr2 = w2 + (long)lane * 128;
    float acc[NPW];
#pragma unroll
    for (int n = 0; n < NPW; ++n) acc[n] = 0.f;
    for (int c = 0; c < 32; ++c) {
        float4 a = *(const float4*)(wr2 + c * 4);
#pragma unroll
        for (int n = 0; n < NPW; ++n) {
            float4 u = *(float4*)&ub[n * 128 + c * 4];
            acc[n] += a.x * u.x + a.y * u.y + a.z * u.z + a.w * u.w;
        }
    }
    float b2v = b2[lane];
#pragma unroll
    for (int n = 0; n < NPW; ++n) {
        long v = nbase + n;
        if (v < N_NODES_C) out[v * 64 + lane] = fmaxf(acc[n] + b2v, 0.f);
    }
}

extern "C" void kernel_launch(void* const* d_in, const int* in_sizes, int n_in,
                              void* d_out, int out_size, void* d_ws, size_t ws_size,
                              hipStream_t stream) {
    const float* x    = (const float*)d_in[0];
    const float* xs   = (const float*)d_in[1];
    const int*   ei   = (const int*)d_in[2];
    const float* ef   = (const float*)d_in[3];
    const float* aw1  = (const float*)d_in[4];
    const float* ab1  = (const float*)d_in[5];
    const float* aw2  = (const float*)d_in[6];
    const float* ab2  = (const float*)d_in[7];
    const float* uw1  = (const float*)d_in[8];
    const float* ub1  = (const float*)d_in[9];
    const float* uw2  = (const float*)d_in[10];
    const float* ub2  = (const float*)d_in[11];
    float* out = (float*)d_out;

    char* ws = (char*)d_ws;
    float* raw     = (float*)(ws + O_RAW);
    int*   deg     = (int*)(ws + O_DEG);
    int*   offsets = (int*)(ws + O_OFF);
    int*   cursor  = (int*)(ws + O_CUR);
    int*   csr_e   = (int*)(ws + O_CSRE);
    int*   csr_src = (int*)(ws + O_CSRS);
    float* agg     = (float*)(ws + O_AGG);

    hipLaunchKernelGGL(k_zero_deg, dim3((N_NODES_C + 255) / 256), dim3(256), 0, stream, deg);
    hipLaunchKernelGGL(k_deg,      dim3((E_C + 255) / 256),       dim3(256), 0, stream, ei, deg);
    hipLaunchKernelGGL(k_scan,     dim3(1),                       dim3(1024), 0, stream, deg, offsets, cursor);
    hipLaunchKernelGGL(k_fill,     dim3((E_C + 255) / 256),       dim3(256), 0, stream, ei, cursor, csr_e, csr_src);
    hipLaunchKernelGGL(k_scores,   dim3(E_C / (4 * EPW)),         dim3(256), 0, stream,
                       x, xs, ei, ef, aw1, ab1, aw2, ab2, raw);
    hipLaunchKernelGGL(k_agg,      dim3((N_NODES_C + 3) / 4),     dim3(256), 0, stream,
                       x, offsets, csr_e, csr_src, raw, agg);
    hipLaunchKernelGGL(k_upd,      dim3((N_NODES_C + 63) / 64),   dim3(256), 0, stream,
                       x, agg, uw1, ub1, uw2, ub2, out);
}

// Round 2
// 573.730 us; speedup vs baseline: 2.5034x; 2.5034x over previous
//
#include <hip/hip_runtime.h>
#include <math.h>

#define N_NODES_C 50000
#define E_C       800000
#define ATT_IN_C  176
#define ATT_HID_C 144

typedef __attribute__((ext_vector_type(8))) __bf16 bf16x8;
typedef __attribute__((ext_vector_type(4))) float f32x4;

// workspace layout (bytes)
#define O_RAW  0L          // float[E]
#define O_DEG  3200000L    // int[N]
#define O_OFF  3400192L    // int[N+1]
#define O_CUR  3600384L    // int[N]
#define O_CSRE 3800576L    // int[E]
#define O_CSRS 7000576L    // int[E]
#define O_AGG  10200576L   // float[N*64]
#define O_XB   23001088L   // bf16[N*64]    6,400,000
#define O_XSB  29401088L   // bf16[N*16]    1,600,000
#define O_EFB  31001088L   // bf16[E*16]   25,600,000
#define O_W1B  56601088L   // bf16[144*176]    50,688  -> total ~54 MB

__device__ __forceinline__ bf16x8 bzero8() {
    bf16x8 z;
#pragma unroll
    for (int i = 0; i < 8; ++i) z[i] = (__bf16)0.0f;
    return z;
}

__global__ __launch_bounds__(256) void k_zero_deg(int* __restrict__ deg) {
    int i = blockIdx.x * blockDim.x + threadIdx.x;
    if (i < N_NODES_C) deg[i] = 0;
}

__global__ __launch_bounds__(256) void k_deg(const int* __restrict__ ei, int* __restrict__ deg) {
    int e = blockIdx.x * blockDim.x + threadIdx.x;
    if (e < E_C) atomicAdd(&deg[ei[E_C + e]], 1);
}

__global__ __launch_bounds__(1024) void k_scan(const int* __restrict__ deg,
                                               int* __restrict__ offsets,
                                               int* __restrict__ cursor) {
    __shared__ int part[1024];
    int t = threadIdx.x;
    const int chunk = (N_NODES_C + 1023) / 1024;
    int lo = t * chunk; if (lo > N_NODES_C) lo = N_NODES_C;
    int hi = lo + chunk; if (hi > N_NODES_C) hi = N_NODES_C;
    int s = 0;
    for (int i = lo; i < hi; ++i) s += deg[i];
    part[t] = s;
    __syncthreads();
    for (int off = 1; off < 1024; off <<= 1) {
        int v = part[t];
        int add = (t >= off) ? part[t - off] : 0;
        __syncthreads();
        part[t] = v + add;
        __syncthreads();
    }
    int run = (t == 0) ? 0 : part[t - 1];
    for (int i = lo; i < hi; ++i) {
        offsets[i] = run;
        cursor[i]  = run;
        run += deg[i];
    }
    if (t == 1023) offsets[N_NODES_C] = part[1023];
}

__global__ __launch_bounds__(256) void k_fill(const int* __restrict__ ei,
                                              int* __restrict__ cursor,
                                              int* __restrict__ csr_e,
                                              int* __restrict__ csr_src) {
    int e = blockIdx.x * blockDim.x + threadIdx.x;
    if (e < E_C) {
        int dst  = ei[E_C + e];
        int slot = atomicAdd(&cursor[dst], 1);
        csr_e[slot]   = e;
        csr_src[slot] = ei[e];
    }
}

// ---- fp32 -> bf16 conversion for x, xs, ef, w1 (one elementwise pass)
__global__ __launch_bounds__(256) void k_cvt(
    const float* __restrict__ x, const float* __restrict__ xs,
    const float* __restrict__ ef, const float* __restrict__ w1,
    __bf16* __restrict__ xb, __bf16* __restrict__ xsb,
    __bf16* __restrict__ efb, __bf16* __restrict__ w1b)
{
    long g = (long)blockIdx.x * 256 + threadIdx.x;  // one group = 8 floats
    const long G_X = 400000, G_XS = 500000, G_EF = 2100000, G_W1 = 2103168;
    if (g >= G_W1) return;
    const float* src; __bf16* dst; long off;
    if (g < G_X)       { src = x;  dst = xb;  off = g * 8; }
    else if (g < G_XS) { src = xs; dst = xsb; off = (g - G_X) * 8; }
    else if (g < G_EF) { src = ef; dst = efb; off = (g - G_XS) * 8; }
    else               { src = w1; dst = w1b; off = (g - G_EF) * 8; }
    float4 a = *(const float4*)(src + off);
    float4 b = *(const float4*)(src + off + 4);
    bf16x8 o;
    o[0] = (__bf16)a.x; o[1] = (__bf16)a.y; o[2] = (__bf16)a.z; o[3] = (__bf16)a.w;
    o[4] = (__bf16)b.x; o[5] = (__bf16)b.y; o[6] = (__bf16)b.z; o[7] = (__bf16)b.w;
    *(bf16x8*)(dst + off) = o;
}

// ---- A-fragment gather: lane's 8 contiguous att_in elems from one source region
__device__ __forceinline__ void load_afrags(
    long t, int mrow, int quad,
    const __bf16* __restrict__ xb, const __bf16* __restrict__ xsb,
    const __bf16* __restrict__ efb, const int* __restrict__ ei,
    bf16x8 a[6])
{
    long e = t * 16 + mrow;
    long src = ei[e], dst = ei[E_C + e];
    const __bf16* px = xb + src * 64 + quad * 8;
    const __bf16* pd = xb + dst * 64 + quad * 8;
    a[0] = *(const bf16x8*)(px);
    a[1] = *(const bf16x8*)(px + 32);
    a[2] = *(const bf16x8*)(pd);
    a[3] = *(const bf16x8*)(pd + 32);
    if (quad < 2) {
        a[4] = *(const bf16x8*)(xsb + src * 16 + quad * 8);
        a[5] = *(const bf16x8*)(efb + e * 16 + quad * 8);
    } else {
        a[4] = *(const bf16x8*)(xsb + dst * 16 + (quad - 2) * 8);
        a[5] = bzero8();
    }
}

// ---- edge attention MLP via bf16 MFMA: raw[e] = leaky(w2 . relu(W1.att_in + b1) + b2)
// GEMM M=E, K=176(pad192), N=144. Wave holds all 54 W1 fragments in VGPRs.
__global__ __launch_bounds__(256) void k_scores_mfma(
    const __bf16* __restrict__ xb, const __bf16* __restrict__ xsb,
    const __bf16* __restrict__ efb, const __bf16* __restrict__ w1b,
    const int* __restrict__ ei,
    const float* __restrict__ b1, const float* __restrict__ w2,
    const float* __restrict__ b2, float* __restrict__ raw)
{
    int tid  = threadIdx.x;
    int lane = tid & 63;
    int w    = blockIdx.x * 4 + (tid >> 6);   // global wave 0..1023
    const int NT = E_C / 16;                  // 50000 tiles, exact
    const int TOT_W = 1024;
    int per = (NT + TOT_W - 1) / TOT_W;       // 49
    long t0 = (long)w * per;
    long t1 = t0 + per; if (t1 > NT) t1 = NT;
    if (t0 >= t1) return;

    int mrow = lane & 15;   // edge-within-tile for A; n-within-tile for B/D cols
    int quad = lane >> 4;

    // B fragments: lane holds W1[n = nt*16+mrow][k0..k0+7], contiguous in W1 row-major
    bf16x8 bfr[6][9];
#pragma unroll
    for (int ks = 0; ks < 6; ++ks) {
        int k0 = ks * 32 + quad * 8;
#pragma unroll
        for (int nt = 0; nt < 9; ++nt) {
            int n = nt * 16 + mrow;
            if (k0 + 8 <= ATT_IN_C)
                bfr[ks][nt] = *(const bf16x8*)(w1b + (long)n * ATT_IN_C + k0);
            else
                bfr[ks][nt] = bzero8();
        }
    }

    // per-lane epilogue constants (n = nt*16 + mrow)
    float b1v[9], w2v[9];
#pragma unroll
    for (int nt = 0; nt < 9; ++nt) {
        int n = nt * 16 + mrow;
        b1v[nt] = b1[n];
        w2v[nt] = w2[n];
    }
    float b2v = b2[0];

    bf16x8 acur[6], anext[6];
    load_afrags(t0, mrow, quad, xb, xsb, efb, ei, acur);

    for (long t = t0; t < t1; ++t) {
        if (t + 1 < t1) load_afrags(t + 1, mrow, quad, xb, xsb, efb, ei, anext);

        f32x4 acc[9];
#pragma unroll
        for (int nt = 0; nt < 9; ++nt) acc[nt] = (f32x4){0.f, 0.f, 0.f, 0.f};

#pragma unroll
        for (int ks = 0; ks < 6; ++ks) {
#pragma unroll
            for (int nt = 0; nt < 9; ++nt) {
                acc[nt] = __builtin_amdgcn_mfma_f32_16x16x32_bf16(
                    acur[ks], bfr[ks][nt], acc[nt], 0, 0, 0);
            }
        }

        // epilogue: h = relu(acc + b1); partial second-layer dot per lane
        // D layout: lane holds D[m = quad*4 + r][n = nt*16 + mrow], r = 0..3
        float p0 = 0.f, p1 = 0.f, p2 = 0.f, p3 = 0.f;
#pragma unroll
        for (int nt = 0; nt < 9; ++nt) {
            p0 += w2v[nt] * fmaxf(acc[nt][0] + b1v[nt], 0.f);
            p1 += w2v[nt] * fmaxf(acc[nt][1] + b1v[nt], 0.f);
            p2 += w2v[nt] * fmaxf(acc[nt][2] + b1v[nt], 0.f);
            p3 += w2v[nt] * fmaxf(acc[nt][3] + b1v[nt], 0.f);
        }
        // reduce across the 16 lanes of each quad-group (low 4 lane bits)
#pragma unroll
        for (int off = 1; off < 16; off <<= 1) {
            p0 += __shfl_xor(p0, off, 64);
            p1 += __shfl_xor(p1, off, 64);
            p2 += __shfl_xor(p2, off, 64);
            p3 += __shfl_xor(p3, off, 64);
        }
        if (mrow < 4) {
            float v = (mrow == 0) ? p0 : (mrow == 1) ? p1 : (mrow == 2) ? p2 : p3;
            v += b2v;
            v = (v >= 0.f) ? v : 0.01f * v;
            raw[t * 16 + quad * 4 + mrow] = v;
        }

#pragma unroll
        for (int i = 0; i < 6; ++i) acur[i] = anext[i];
    }
}

// ---- per-node segment softmax + weighted gather
__global__ __launch_bounds__(256) void k_agg(
    const float* __restrict__ x, const int* __restrict__ offsets,
    const int* __restrict__ csr_e, const int* __restrict__ csr_src,
    const float* __restrict__ raw, float* __restrict__ agg)
{
    int tid = threadIdx.x;
    int wave = tid >> 6, lane = tid & 63;
    int v = blockIdx.x * 4 + wave;
    if (v >= N_NODES_C) return;
    int s0 = offsets[v], s1 = offsets[v + 1];

    float m = -INFINITY;
    for (int p = s0 + lane; p < s1; p += 64) m = fmaxf(m, raw[csr_e[p]]);
#pragma unroll
    for (int off = 32; off > 0; off >>= 1) m = fmaxf(m, __shfl_xor(m, off, 64));

    float acc = 0.f, sum = 0.f;
    for (int p = s0; p < s1; ++p) {
        int e   = csr_e[p];
        int src = csr_src[p];
        float w = expf(raw[e] - m);
        sum += w;
        acc += w * x[(long)src * 64 + lane];
    }
    agg[(long)v * 64 + lane] = acc / (sum + 1e-9f);
}

// ---- node update MLP
#define NPW 16
__global__ __launch_bounds__(256) void k_upd(
    const float* __restrict__ x, const float* __restrict__ agg,
    const float* __restrict__ w1, const float* __restrict__ b1,
    const float* __restrict__ w2, const float* __restrict__ b2,
    float* __restrict__ out)
{
    __shared__ float inbuf[4][NPW * 128];
    __shared__ float ubuf[4][NPW * 128];
    int tid = threadIdx.x;
    int wave = tid >> 6, lane = tid & 63;
    long nbase = ((long)blockIdx.x * 4 + wave) * NPW;
    float* ib = inbuf[wave];
    float* ub = ubuf[wave];

#pragma unroll
    for (int it = 0; it < 8; ++it) {
        int idx = it * 64 + lane;
        int nl = idx >> 5, c = idx & 31;
        long v  = nbase + nl;
        long vc = v < (N_NODES_C - 1) ? v : (N_NODES_C - 1);
        const float* p = (c < 16) ? (x + vc * 64 + c * 4)
                                  : (agg + vc * 64 + (c - 16) * 4);
        *(float4*)&ib[nl * 128 + c * 4] = *(const float4*)p;
    }
    __syncthreads();

    const float* wr0 = w1 + (long)lane * 128;
    const float* wr1 = w1 + (long)(lane + 64) * 128;
    float acc0[NPW], acc1[NPW];
#pragma unroll
    for (int n = 0; n < NPW; ++n) { acc0[n] = 0.f; acc1[n] = 0.f; }
    for (int c = 0; c < 32; ++c) {
        float4 a = *(const float4*)(wr0 + c * 4);
        float4 b = *(const float4*)(wr1 + c * 4);
#pragma unroll
        for (int n = 0; n < NPW; ++n) {
            float4 v = *(float4*)&ib[n * 128 + c * 4];
            acc0[n] += a.x * v.x + a.y * v.y + a.z * v.z + a.w * v.w;
            acc1[n] += b.x * v.x + b.y * v.y + b.z * v.z + b.w * v.w;
        }
    }
    float b10 = b1[lane], b11 = b1[lane + 64];
#pragma unroll
    for (int n = 0; n < NPW; ++n) {
        ub[n * 128 + lane]      = fmaxf(acc0[n] + b10, 0.f);
        ub[n * 128 + 64 + lane] = fmaxf(acc1[n] + b11, 0.f);
    }
    __syncthreads();

    const float* wr2 = w2 + (long)lane * 128;
    float acc[NPW];
#pragma unroll
    for (int n = 0; n < NPW; ++n) acc[n] = 0.f;
    for (int c = 0; c < 32; ++c) {
        float4 a = *(const float4*)(wr2 + c * 4);
#pragma unroll
        for (int n = 0; n < NPW; ++n) {
            float4 u = *(float4*)&ub[n * 128 + c * 4];
            acc[n] += a.x * u.x + a.y * u.y + a.z * u.z + a.w * u.w;
        }
    }
    float b2v = b2[lane];
#pragma unroll
    for (int n = 0; n < NPW; ++n) {
        long v = nbase + n;
        if (v < N_NODES_C) out[v * 64 + lane] = fmaxf(acc[n] + b2v, 0.f);
    }
}

extern "C" void kernel_launch(void* const* d_in, const int* in_sizes, int n_in,
                              void* d_out, int out_size, void* d_ws, size_t ws_size,
                              hipStream_t stream) {
    const float* x    = (const float*)d_in[0];
    const float* xs   = (const float*)d_in[1];
    const int*   ei   = (const int*)d_in[2];
    const float* ef   = (const float*)d_in[3];
    const float* aw1  = (const float*)d_in[4];
    const float* ab1  = (const float*)d_in[5];
    const float* aw2  = (const float*)d_in[6];
    const float* ab2  = (const float*)d_in[7];
    const float* uw1  = (const float*)d_in[8];
    const float* ub1  = (const float*)d_in[9];
    const float* uw2  = (const float*)d_in[10];
    const float* ub2  = (const float*)d_in[11];
    float* out = (float*)d_out;

    char* ws = (char*)d_ws;
    float*  raw     = (float*)(ws + O_RAW);
    int*    deg     = (int*)(ws + O_DEG);
    int*    offsets = (int*)(ws + O_OFF);
    int*    cursor  = (int*)(ws + O_CUR);
    int*    csr_e   = (int*)(ws + O_CSRE);
    int*    csr_src = (int*)(ws + O_CSRS);
    float*  agg     = (float*)(ws + O_AGG);
    __bf16* xb      = (__bf16*)(ws + O_XB);
    __bf16* xsb     = (__bf16*)(ws + O_XSB);
    __bf16* efb     = (__bf16*)(ws + O_EFB);
    __bf16* w1b     = (__bf16*)(ws + O_W1B);

    hipLaunchKernelGGL(k_zero_deg, dim3((N_NODES_C + 255) / 256), dim3(256), 0, stream, deg);
    hipLaunchKernelGGL(k_deg,      dim3((E_C + 255) / 256),       dim3(256), 0, stream, ei, deg);
    hipLaunchKernelGGL(k_scan,     dim3(1),                       dim3(1024), 0, stream, deg, offsets, cursor);
    hipLaunchKernelGGL(k_fill,     dim3((E_C + 255) / 256),       dim3(256), 0, stream, ei, cursor, csr_e, csr_src);
    hipLaunchKernelGGL(k_cvt,      dim3(8216),                    dim3(256), 0, stream,
                       x, xs, ef, aw1, xb, xsb, efb, w1b);
    hipLaunchKernelGGL(k_scores_mfma, dim3(256),                  dim3(256), 0, stream,
                       xb, xsb, efb, w1b, ei, ab1, aw2, ab2, raw);
    hipLaunchKernelGGL(k_agg,      dim3((N_NODES_C + 3) / 4),     dim3(256), 0, stream,
                       x, offsets, csr_e, csr_src, raw, agg);
    hipLaunchKernelGGL(k_upd,      dim3((N_NODES_C + 63) / 64),   dim3(256), 0, stream,
                       x, agg, uw1, ub1, uw2, ub2, out);
}

// Round 3
// 473.999 us; speedup vs baseline: 3.0301x; 1.2104x over previous
//
#include <hip/hip_runtime.h>
#include <math.h>

#define N_NODES_C 50000
#define E_C       800000
#define ATT_IN_C  176
#define ATT_HID_C 144
#define SCAN_B    98   // ceil(50000 / 512)

typedef __attribute__((ext_vector_type(8))) __bf16 bf16x8;
typedef __attribute__((ext_vector_type(4))) float f32x4;

// workspace layout (bytes)
#define O_RAW  0L          // float[E]
#define O_DEG  3200000L    // int[N]
#define O_OFF  3400192L    // int[N+1]
#define O_CUR  3600384L    // int[N]
#define O_CSRE 3800576L    // int[E]
#define O_CSRS 7000576L    // int[E]
#define O_AGG  10200576L   // float[N*64]   (psum/boff borrow the head of this
                           //                region; agg is written much later)
#define O_PSUM O_AGG             // int[128]
#define O_BOFF (O_AGG + 512L)    // int[130]
#define O_XB   23001088L   // bf16[N*64]
#define O_XSB  29401088L   // bf16[N*16]
#define O_EFB  31001088L   // bf16[E*16]
#define O_W1B  56601088L   // bf16[144*176]

__device__ __forceinline__ bf16x8 bzero8() {
    bf16x8 z;
#pragma unroll
    for (int i = 0; i < 8; ++i) z[i] = (__bf16)0.0f;
    return z;
}

__global__ __launch_bounds__(256) void k_zero_deg(int* __restrict__ deg) {
    int i = blockIdx.x * blockDim.x + threadIdx.x;
    if (i < N_NODES_C) deg[i] = 0;
}

__global__ __launch_bounds__(256) void k_deg(const int* __restrict__ ei, int* __restrict__ deg) {
    int e = blockIdx.x * blockDim.x + threadIdx.x;
    if (e < E_C) atomicAdd(&deg[ei[E_C + e]], 1);
}

// ---- 3-phase parallel scan of deg -> offsets/cursor
__global__ __launch_bounds__(256) void k_scan1(const int* __restrict__ deg,
                                               int* __restrict__ psum) {
    __shared__ int red[256];
    int b = blockIdx.x, t = threadIdx.x;
    int i = b * 512 + t * 2;
    int s = 0;
    if (i < N_NODES_C) s += deg[i];
    if (i + 1 < N_NODES_C) s += deg[i + 1];
    red[t] = s;
    __syncthreads();
#pragma unroll
    for (int off = 128; off > 0; off >>= 1) {
        if (t < off) red[t] += red[t + off];
        __syncthreads();
    }
    if (t == 0) psum[b] = red[0];
}

__global__ __launch_bounds__(128) void k_scan2(const int* __restrict__ psum,
                                               int* __restrict__ boff,
                                               int* __restrict__ offsets) {
    __shared__ int sc[128];
    int t = threadIdx.x;
    int v = (t < SCAN_B) ? psum[t] : 0;
    sc[t] = v;
    __syncthreads();
#pragma unroll
    for (int off = 1; off < 128; off <<= 1) {
        int val = sc[t];
        int add = (t >= off) ? sc[t - off] : 0;
        __syncthreads();
        sc[t] = val + add;
        __syncthreads();
    }
    boff[t] = sc[t] - v;  // exclusive prefix
    if (t == SCAN_B - 1) offsets[N_NODES_C] = sc[t];
}

__global__ __launch_bounds__(256) void k_scan3(const int* __restrict__ deg,
                                               const int* __restrict__ boff,
                                               int* __restrict__ offsets,
                                               int* __restrict__ cursor) {
    __shared__ int sc[256];
    int b = blockIdx.x, t = threadIdx.x;
    int i = b * 512 + t * 2;
    int d0 = (i < N_NODES_C) ? deg[i] : 0;
    int d1 = (i + 1 < N_NODES_C) ? deg[i + 1] : 0;
    int s = d0 + d1;
    sc[t] = s;
    __syncthreads();
#pragma unroll
    for (int off = 1; off < 256; off <<= 1) {
        int val = sc[t];
        int add = (t >= off) ? sc[t - off] : 0;
        __syncthreads();
        sc[t] = val + add;
        __syncthreads();
    }
    int excl = boff[b] + sc[t] - s;
    if (i < N_NODES_C)     { offsets[i]     = excl;      cursor[i]     = excl; }
    if (i + 1 < N_NODES_C) { offsets[i + 1] = excl + d0; cursor[i + 1] = excl + d0; }
}

__global__ __launch_bounds__(256) void k_fill(const int* __restrict__ ei,
                                              int* __restrict__ cursor,
                                              int* __restrict__ csr_e,
                                              int* __restrict__ csr_src) {
    int e = blockIdx.x * blockDim.x + threadIdx.x;
    if (e < E_C) {
        int dst  = ei[E_C + e];
        int slot = atomicAdd(&cursor[dst], 1);
        csr_e[slot]   = e;
        csr_src[slot] = ei[e];
    }
}

// ---- fp32 -> bf16 conversion for x, xs, ef, w1
__global__ __launch_bounds__(256) void k_cvt(
    const float* __restrict__ x, const float* __restrict__ xs,
    const float* __restrict__ ef, const float* __restrict__ w1,
    __bf16* __restrict__ xb, __bf16* __restrict__ xsb,
    __bf16* __restrict__ efb, __bf16* __restrict__ w1b)
{
    long g = (long)blockIdx.x * 256 + threadIdx.x;  // one group = 8 floats
    const long G_X = 400000, G_XS = 500000, G_EF = 2100000, G_W1 = 2103168;
    if (g >= G_W1) return;
    const float* src; __bf16* dst; long off;
    if (g < G_X)       { src = x;  dst = xb;  off = g * 8; }
    else if (g < G_XS) { src = xs; dst = xsb; off = (g - G_X) * 8; }
    else if (g < G_EF) { src = ef; dst = efb; off = (g - G_XS) * 8; }
    else               { src = w1; dst = w1b; off = (g - G_EF) * 8; }
    float4 a = *(const float4*)(src + off);
    float4 b = *(const float4*)(src + off + 4);
    bf16x8 o;
    o[0] = (__bf16)a.x; o[1] = (__bf16)a.y; o[2] = (__bf16)a.z; o[3] = (__bf16)a.w;
    o[4] = (__bf16)b.x; o[5] = (__bf16)b.y; o[6] = (__bf16)b.z; o[7] = (__bf16)b.w;
    *(bf16x8*)(dst + off) = o;
}

// ---- A-fragment gather with precomputed src/dst
__device__ __forceinline__ void load_afrags(
    int src, int dst, long t, int mrow, int quad,
    const __bf16* __restrict__ xb, const __bf16* __restrict__ xsb,
    const __bf16* __restrict__ efb,
    bf16x8 a[6])
{
    long e = t * 16 + mrow;
    const __bf16* px = xb + (long)src * 64 + quad * 8;
    const __bf16* pd = xb + (long)dst * 64 + quad * 8;
    a[0] = *(const bf16x8*)(px);
    a[1] = *(const bf16x8*)(px + 32);
    a[2] = *(const bf16x8*)(pd);
    a[3] = *(const bf16x8*)(pd + 32);
    if (quad < 2) {
        a[4] = *(const bf16x8*)(xsb + (long)src * 16 + quad * 8);
        a[5] = *(const bf16x8*)(efb + e * 16 + quad * 8);
    } else {
        a[4] = *(const bf16x8*)(xsb + (long)dst * 16 + (quad - 2) * 8);
        a[5] = bzero8();
    }
}

// ---- edge attention MLP via bf16 MFMA
// Pipeline: ei prefetched 2 tiles ahead, data gathers ~2 iterations ahead.
__global__ __launch_bounds__(256) void k_scores_mfma(
    const __bf16* __restrict__ xb, const __bf16* __restrict__ xsb,
    const __bf16* __restrict__ efb, const __bf16* __restrict__ w1b,
    const int* __restrict__ ei,
    const float* __restrict__ b1, const float* __restrict__ w2,
    const float* __restrict__ b2, float* __restrict__ raw)
{
    int tid  = threadIdx.x;
    int lane = tid & 63;
    int w    = blockIdx.x * 4 + (tid >> 6);   // global wave 0..1023
    const int NT = E_C / 16;
    const int TOT_W = 1024;
    int per = (NT + TOT_W - 1) / TOT_W;       // 49
    long t0 = (long)w * per;
    long t1 = t0 + per; if (t1 > NT) t1 = NT;
    if (t0 >= t1) return;

    int mrow = lane & 15;
    int quad = lane >> 4;

    // B fragments: lane holds W1[n = nt*16+mrow][k0..k0+7]
    bf16x8 bfr[6][9];
#pragma unroll
    for (int ks = 0; ks < 6; ++ks) {
        int k0 = ks * 32 + quad * 8;
#pragma unroll
        for (int nt = 0; nt < 9; ++nt) {
            int n = nt * 16 + mrow;
            if (k0 + 8 <= ATT_IN_C)
                bfr[ks][nt] = *(const bf16x8*)(w1b + (long)n * ATT_IN_C + k0);
            else
                bfr[ks][nt] = bzero8();
        }
    }

    float b1v[9], w2v[9];
#pragma unroll
    for (int nt = 0; nt < 9; ++nt) {
        int n = nt * 16 + mrow;
        b1v[nt] = b1[n];
        w2v[nt] = w2[n];
    }
    float b2v = b2[0];

    // --- pipeline setup ---
    bf16x8 acur[6], anext[6];
    int ns = 0, nd = 0;   // ei for the tile whose data loads next (t+2 slot)
    {
        long e0 = t0 * 16 + mrow;
        int cs = ei[e0], cd = ei[E_C + e0];
        load_afrags(cs, cd, t0, mrow, quad, xb, xsb, efb, acur);
        if (t0 + 1 < t1) {
            long e1 = (t0 + 1) * 16 + mrow;
            int s1 = ei[e1], d1 = ei[E_C + e1];
            load_afrags(s1, d1, t0 + 1, mrow, quad, xb, xsb, efb, anext);
        }
    }

    for (long t = t0; t < t1; ++t) {
        // prefetch edge indices for t+2 (no dependencies, 2 iterations to land)
        if (t + 2 < t1) {
            long e2 = (t + 2) * 16 + mrow;
            ns = ei[e2];
            nd = ei[E_C + e2];
        }

        f32x4 acc[9];
#pragma unroll
        for (int nt = 0; nt < 9; ++nt) acc[nt] = (f32x4){0.f, 0.f, 0.f, 0.f};

#pragma unroll
        for (int ks = 0; ks < 6; ++ks) {
#pragma unroll
            for (int nt = 0; nt < 9; ++nt) {
                acc[nt] = __builtin_amdgcn_mfma_f32_16x16x32_bf16(
                    acur[ks], bfr[ks][nt], acc[nt], 0, 0, 0);
            }
        }

        // epilogue: per-lane partial of layer-2 dot over its 9 n-values
        float p0 = 0.f, p1 = 0.f, p2 = 0.f, p3 = 0.f;
#pragma unroll
        for (int nt = 0; nt < 9; ++nt) {
            p0 += w2v[nt] * fmaxf(acc[nt][0] + b1v[nt], 0.f);
            p1 += w2v[nt] * fmaxf(acc[nt][1] + b1v[nt], 0.f);
            p2 += w2v[nt] * fmaxf(acc[nt][2] + b1v[nt], 0.f);
            p3 += w2v[nt] * fmaxf(acc[nt][3] + b1v[nt], 0.f);
        }
#pragma unroll
        for (int off = 1; off < 16; off <<= 1) {
            p0 += __shfl_xor(p0, off, 64);
            p1 += __shfl_xor(p1, off, 64);
            p2 += __shfl_xor(p2, off, 64);
            p3 += __shfl_xor(p3, off, 64);
        }
        if (mrow < 4) {
            float v = (mrow == 0) ? p0 : (mrow == 1) ? p1 : (mrow == 2) ? p2 : p3;
            v += b2v;
            v = (v >= 0.f) ? v : 0.01f * v;
            raw[t * 16 + quad * 4 + mrow] = v;
        }

        // rotate; issue data gathers for t+2 (land during iteration t+1)
#pragma unroll
        for (int i = 0; i < 6; ++i) acur[i] = anext[i];
        if (t + 2 < t1)
            load_afrags(ns, nd, t + 2, mrow, quad, xb, xsb, efb, anext);
    }
}

// ---- per-node segment softmax + weighted gather
__global__ __launch_bounds__(256) void k_agg(
    const float* __restrict__ x, const int* __restrict__ offsets,
    const int* __restrict__ csr_e, const int* __restrict__ csr_src,
    const float* __restrict__ raw, float* __restrict__ agg)
{
    int tid = threadIdx.x;
    int wave = tid >> 6, lane = tid & 63;
    int v = blockIdx.x * 4 + wave;
    if (v >= N_NODES_C) return;
    int s0 = offsets[v], s1 = offsets[v + 1];

    float m = -INFINITY;
    for (int p = s0 + lane; p < s1; p += 64) m = fmaxf(m, raw[csr_e[p]]);
#pragma unroll
    for (int off = 32; off > 0; off >>= 1) m = fmaxf(m, __shfl_xor(m, off, 64));

    float acc = 0.f, sum = 0.f;
    for (int p = s0; p < s1; ++p) {
        int e   = csr_e[p];
        int src = csr_src[p];
        float w = expf(raw[e] - m);
        sum += w;
        acc += w * x[(long)src * 64 + lane];
    }
    agg[(long)v * 64 + lane] = acc / (sum + 1e-9f);
}

// ---- node update MLP (fp32 shared-mem GEMM)
#define NPW 16
__global__ __launch_bounds__(256) void k_upd(
    const float* __restrict__ x, const float* __restrict__ agg,
    const float* __restrict__ w1, const float* __restrict__ b1,
    const float* __restrict__ w2, const float* __restrict__ b2,
    float* __restrict__ out)
{
    __shared__ float inbuf[4][NPW * 128];
    __shared__ float ubuf[4][NPW * 128];
    int tid = threadIdx.x;
    int wave = tid >> 6, lane = tid & 63;
    long nbase = ((long)blockIdx.x * 4 + wave) * NPW;
    float* ib = inbuf[wave];
    float* ub = ubuf[wave];

#pragma unroll
    for (int it = 0; it < 8; ++it) {
        int idx = it * 64 + lane;
        int nl = idx >> 5, c = idx & 31;
        long v  = nbase + nl;
        long vc = v < (N_NODES_C - 1) ? v : (N_NODES_C - 1);
        const float* p = (c < 16) ? (x + vc * 64 + c * 4)
                                  : (agg + vc * 64 + (c - 16) * 4);
        *(float4*)&ib[nl * 128 + c * 4] = *(const float4*)p;
    }
    __syncthreads();

    const float* wr0 = w1 + (long)lane * 128;
    const float* wr1 = w1 + (long)(lane + 64) * 128;
    float acc0[NPW], acc1[NPW];
#pragma unroll
    for (int n = 0; n < NPW; ++n) { acc0[n] = 0.f; acc1[n] = 0.f; }
    for (int c = 0; c < 32; ++c) {
        float4 a = *(const float4*)(wr0 + c * 4);
        float4 b = *(const float4*)(wr1 + c * 4);
#pragma unroll
        for (int n = 0; n < NPW; ++n) {
            float4 v = *(float4*)&ib[n * 128 + c * 4];
            acc0[n] += a.x * v.x + a.y * v.y + a.z * v.z + a.w * v.w;
            acc1[n] += b.x * v.x + b.y * v.y + b.z * v.z + b.w * v.w;
        }
    }
    float b10 = b1[lane], b11 = b1[lane + 64];
#pragma unroll
    for (int n = 0; n < NPW; ++n) {
        ub[n * 128 + lane]      = fmaxf(acc0[n] + b10, 0.f);
        ub[n * 128 + 64 + lane] = fmaxf(acc1[n] + b11, 0.f);
    }
    __syncthreads();

    const float* wr2 = w2 + (long)lane * 128;
    float acc[NPW];
#pragma unroll
    for (int n = 0; n < NPW; ++n) acc[n] = 0.f;
    for (int c = 0; c < 32; ++c) {
        float4 a = *(const float4*)(wr2 + c * 4);
#pragma unroll
        for (int n = 0; n < NPW; ++n) {
            float4 u = *(float4*)&ub[n * 128 + c * 4];
            acc[n] += a.x * u.x + a.y * u.y + a.z * u.z + a.w * u.w;
        }
    }
    float b2v = b2[lane];
#pragma unroll
    for (int n = 0; n < NPW; ++n) {
        long v = nbase + n;
        if (v < N_NODES_C) out[v * 64 + lane] = fmaxf(acc[n] + b2v, 0.f);
    }
}

extern "C" void kernel_launch(void* const* d_in, const int* in_sizes, int n_in,
                              void* d_out, int out_size, void* d_ws, size_t ws_size,
                              hipStream_t stream) {
    const float* x    = (const float*)d_in[0];
    const float* xs   = (const float*)d_in[1];
    const int*   ei   = (const int*)d_in[2];
    const float* ef   = (const float*)d_in[3];
    const float* aw1  = (const float*)d_in[4];
    const float* ab1  = (const float*)d_in[5];
    const float* aw2  = (const float*)d_in[6];
    const float* ab2  = (const float*)d_in[7];
    const float* uw1  = (const float*)d_in[8];
    const float* ub1  = (const float*)d_in[9];
    const float* uw2  = (const float*)d_in[10];
    const float* ub2  = (const float*)d_in[11];
    float* out = (float*)d_out;

    char* ws = (char*)d_ws;
    float*  raw     = (float*)(ws + O_RAW);
    int*    deg     = (int*)(ws + O_DEG);
    int*    offsets = (int*)(ws + O_OFF);
    int*    cursor  = (int*)(ws + O_CUR);
    int*    csr_e   = (int*)(ws + O_CSRE);
    int*    csr_src = (int*)(ws + O_CSRS);
    float*  agg     = (float*)(ws + O_AGG);
    int*    psum    = (int*)(ws + O_PSUM);
    int*    boff    = (int*)(ws + O_BOFF);
    __bf16* xb      = (__bf16*)(ws + O_XB);
    __bf16* xsb     = (__bf16*)(ws + O_XSB);
    __bf16* efb     = (__bf16*)(ws + O_EFB);
    __bf16* w1b     = (__bf16*)(ws + O_W1B);

    hipLaunchKernelGGL(k_zero_deg, dim3((N_NODES_C + 255) / 256), dim3(256), 0, stream, deg);
    hipLaunchKernelGGL(k_deg,      dim3((E_C + 255) / 256),       dim3(256), 0, stream, ei, deg);
    hipLaunchKernelGGL(k_scan1,    dim3(SCAN_B),                  dim3(256), 0, stream, deg, psum);
    hipLaunchKernelGGL(k_scan2,    dim3(1),                       dim3(128), 0, stream, psum, boff, offsets);
    hipLaunchKernelGGL(k_scan3,    dim3(SCAN_B),                  dim3(256), 0, stream, deg, boff, offsets, cursor);
    hipLaunchKernelGGL(k_fill,     dim3((E_C + 255) / 256),       dim3(256), 0, stream, ei, cursor, csr_e, csr_src);
    hipLaunchKernelGGL(k_cvt,      dim3(8216),                    dim3(256), 0, stream,
                       x, xs, ef, aw1, xb, xsb, efb, w1b);
    hipLaunchKernelGGL(k_scores_mfma, dim3(256),                  dim3(256), 0, stream,
                       xb, xsb, efb, w1b, ei, ab1, aw2, ab2, raw);
    hipLaunchKernelGGL(k_agg,      dim3((N_NODES_C + 3) / 4),     dim3(256), 0, stream,
                       x, offsets, csr_e, csr_src, raw, agg);
    hipLaunchKernelGGL(k_upd,      dim3((N_NODES_C + 63) / 64),   dim3(256), 0, stream,
                       x, agg, uw1, ub1, uw2, ub2, out);
}

// Round 4
// 409.669 us; speedup vs baseline: 3.5059x; 1.1570x over previous
//
#include <hip/hip_runtime.h>
#include <math.h>

#define N_NODES_C 50000
#define E_C       800000
#define ATT_IN_C  176
#define ATT_HID_C 144
#define SCAN_B    98      // ceil(50000 / 512)
#define UPD_TILES 3125    // 50000 / 16 exact

typedef __attribute__((ext_vector_type(8))) __bf16 bf16x8;
typedef __attribute__((ext_vector_type(4))) float f32x4;

// workspace layout (bytes, 1KB aligned)
#define O_RAW   0L          // float[E]       3,200,000
#define O_DEG   3201024L    // int[N]
#define O_OFF   3402752L    // int[N+1]
#define O_CUR   3603456L    // int[N]
#define O_CSRS  3804160L    // int[E] src per CSR slot
#define O_CSRD  7005184L    // int[E] dst per CSR slot
#define O_EFP   10206208L   // bf16[E*16] permuted edge features
#define O_XB    35807232L   // bf16[N*64]
#define O_XSB   42208256L   // bf16[N*16]
#define O_W1B   43809280L   // bf16[144*176]
#define O_UW1B  43860992L   // bf16[128*128]
#define O_UW2B  43894784L   // bf16[64*128]
#define O_AGGB  43912192L   // bf16[N*64]  (psum/boff borrow head; dead by k_agg)
#define O_PSUM  O_AGGB
#define O_BOFF  (O_AGGB + 512L)

__device__ __forceinline__ bf16x8 bzero8() {
    bf16x8 z;
#pragma unroll
    for (int i = 0; i < 8; ++i) z[i] = (__bf16)0.0f;
    return z;
}

__global__ __launch_bounds__(256) void k_zero_deg(int* __restrict__ deg) {
    int i = blockIdx.x * blockDim.x + threadIdx.x;
    if (i < N_NODES_C) deg[i] = 0;
}

__global__ __launch_bounds__(256) void k_deg(const int* __restrict__ ei, int* __restrict__ deg) {
    int e = blockIdx.x * blockDim.x + threadIdx.x;
    if (e < E_C) atomicAdd(&deg[ei[E_C + e]], 1);
}

// ---- 3-phase parallel scan of deg -> offsets/cursor
__global__ __launch_bounds__(256) void k_scan1(const int* __restrict__ deg,
                                               int* __restrict__ psum) {
    __shared__ int red[256];
    int b = blockIdx.x, t = threadIdx.x;
    int i = b * 512 + t * 2;
    int s = 0;
    if (i < N_NODES_C) s += deg[i];
    if (i + 1 < N_NODES_C) s += deg[i + 1];
    red[t] = s;
    __syncthreads();
#pragma unroll
    for (int off = 128; off > 0; off >>= 1) {
        if (t < off) red[t] += red[t + off];
        __syncthreads();
    }
    if (t == 0) psum[b] = red[0];
}

__global__ __launch_bounds__(128) void k_scan2(const int* __restrict__ psum,
                                               int* __restrict__ boff,
                                               int* __restrict__ offsets) {
    __shared__ int sc[128];
    int t = threadIdx.x;
    int v = (t < SCAN_B) ? psum[t] : 0;
    sc[t] = v;
    __syncthreads();
#pragma unroll
    for (int off = 1; off < 128; off <<= 1) {
        int val = sc[t];
        int add = (t >= off) ? sc[t - off] : 0;
        __syncthreads();
        sc[t] = val + add;
        __syncthreads();
    }
    boff[t] = sc[t] - v;
    if (t == SCAN_B - 1) offsets[N_NODES_C] = sc[t];
}

__global__ __launch_bounds__(256) void k_scan3(const int* __restrict__ deg,
                                               const int* __restrict__ boff,
                                               int* __restrict__ offsets,
                                               int* __restrict__ cursor) {
    __shared__ int sc[256];
    int b = blockIdx.x, t = threadIdx.x;
    int i = b * 512 + t * 2;
    int d0 = (i < N_NODES_C) ? deg[i] : 0;
    int d1 = (i + 1 < N_NODES_C) ? deg[i + 1] : 0;
    int s = d0 + d1;
    sc[t] = s;
    __syncthreads();
#pragma unroll
    for (int off = 1; off < 256; off <<= 1) {
        int val = sc[t];
        int add = (t >= off) ? sc[t - off] : 0;
        __syncthreads();
        sc[t] = val + add;
        __syncthreads();
    }
    int excl = boff[b] + sc[t] - s;
    if (i < N_NODES_C)     { offsets[i]     = excl;      cursor[i]     = excl; }
    if (i + 1 < N_NODES_C) { offsets[i + 1] = excl + d0; cursor[i + 1] = excl + d0; }
}

// ---- CSR fill + ef permute/convert (ef read coalesced, written scattered bf16)
__global__ __launch_bounds__(256) void k_fill(const int* __restrict__ ei,
                                              const float* __restrict__ ef,
                                              int* __restrict__ cursor,
                                              int* __restrict__ csr_src,
                                              int* __restrict__ csr_dst,
                                              __bf16* __restrict__ efp) {
    int e = blockIdx.x * blockDim.x + threadIdx.x;
    if (e < E_C) {
        int src  = ei[e];
        int dst  = ei[E_C + e];
        int slot = atomicAdd(&cursor[dst], 1);
        csr_src[slot] = src;
        csr_dst[slot] = dst;
        const float4* pe = (const float4*)(ef + (long)e * 16);
        float4 f0 = pe[0], f1 = pe[1], f2 = pe[2], f3 = pe[3];
        bf16x8 o0, o1;
        o0[0] = (__bf16)f0.x; o0[1] = (__bf16)f0.y; o0[2] = (__bf16)f0.z; o0[3] = (__bf16)f0.w;
        o0[4] = (__bf16)f1.x; o0[5] = (__bf16)f1.y; o0[6] = (__bf16)f1.z; o0[7] = (__bf16)f1.w;
        o1[0] = (__bf16)f2.x; o1[1] = (__bf16)f2.y; o1[2] = (__bf16)f2.z; o1[3] = (__bf16)f2.w;
        o1[4] = (__bf16)f3.x; o1[5] = (__bf16)f3.y; o1[6] = (__bf16)f3.z; o1[7] = (__bf16)f3.w;
        *(bf16x8*)(efp + (long)slot * 16)     = o0;
        *(bf16x8*)(efp + (long)slot * 16 + 8) = o1;
    }
}

// ---- fp32 -> bf16 conversion: x, xs, att_w1, upd_w1, upd_w2
__global__ __launch_bounds__(256) void k_cvt(
    const float* __restrict__ x, const float* __restrict__ xs,
    const float* __restrict__ w1, const float* __restrict__ uw1,
    const float* __restrict__ uw2,
    __bf16* __restrict__ xb, __bf16* __restrict__ xsb,
    __bf16* __restrict__ w1b, __bf16* __restrict__ uw1b,
    __bf16* __restrict__ uw2b)
{
    long g = (long)blockIdx.x * 256 + threadIdx.x;  // one group = 8 floats
    const long G_X = 400000, G_XS = 500000, G_W1 = 503168, G_UW1 = 505216, G_UW2 = 506240;
    if (g >= G_UW2) return;
    const float* src; __bf16* dst; long off;
    if (g < G_X)        { src = x;   dst = xb;   off = g * 8; }
    else if (g < G_XS)  { src = xs;  dst = xsb;  off = (g - G_X) * 8; }
    else if (g < G_W1)  { src = w1;  dst = w1b;  off = (g - G_XS) * 8; }
    else if (g < G_UW1) { src = uw1; dst = uw1b; off = (g - G_W1) * 8; }
    else                { src = uw2; dst = uw2b; off = (g - G_UW1) * 8; }
    float4 a = *(const float4*)(src + off);
    float4 b = *(const float4*)(src + off + 4);
    bf16x8 o;
    o[0] = (__bf16)a.x; o[1] = (__bf16)a.y; o[2] = (__bf16)a.z; o[3] = (__bf16)a.w;
    o[4] = (__bf16)b.x; o[5] = (__bf16)b.y; o[6] = (__bf16)b.z; o[7] = (__bf16)b.w;
    *(bf16x8*)(dst + off) = o;
}

// ---- A-fragment gather (CSR order: p = t*16 + mrow; efp contiguous)
__device__ __forceinline__ void load_afrags(
    int src, int dst, long t, int mrow, int quad,
    const __bf16* __restrict__ xb, const __bf16* __restrict__ xsb,
    const __bf16* __restrict__ efp,
    bf16x8 a[6])
{
    long p = t * 16 + mrow;
    const __bf16* px = xb + (long)src * 64 + quad * 8;
    const __bf16* pd = xb + (long)dst * 64 + quad * 8;
    a[0] = *(const bf16x8*)(px);
    a[1] = *(const bf16x8*)(px + 32);
    a[2] = *(const bf16x8*)(pd);
    a[3] = *(const bf16x8*)(pd + 32);
    if (quad < 2) {
        a[4] = *(const bf16x8*)(xsb + (long)src * 16 + quad * 8);
        a[5] = *(const bf16x8*)(efp + p * 16 + quad * 8);
    } else {
        a[4] = *(const bf16x8*)(xsb + (long)dst * 16 + (quad - 2) * 8);
        a[5] = bzero8();
    }
}

// ---- edge attention MLP via bf16 MFMA, CSR-ordered (dst-locality in gathers)
__global__ __launch_bounds__(256) void k_scores_mfma(
    const __bf16* __restrict__ xb, const __bf16* __restrict__ xsb,
    const __bf16* __restrict__ efp, const __bf16* __restrict__ w1b,
    const int* __restrict__ csr_src, const int* __restrict__ csr_dst,
    const float* __restrict__ b1, const float* __restrict__ w2,
    const float* __restrict__ b2, float* __restrict__ raw)
{
    int tid  = threadIdx.x;
    int lane = tid & 63;
    int w    = blockIdx.x * 4 + (tid >> 6);   // global wave 0..1023
    const int NT = E_C / 16;
    int per = (NT + 1023) / 1024;             // 49
    long t0 = (long)w * per;
    long t1 = t0 + per; if (t1 > NT) t1 = NT;
    if (t0 >= t1) return;

    int mrow = lane & 15;
    int quad = lane >> 4;

    bf16x8 bfr[6][9];
#pragma unroll
    for (int ks = 0; ks < 6; ++ks) {
        int k0 = ks * 32 + quad * 8;
#pragma unroll
        for (int nt = 0; nt < 9; ++nt) {
            int n = nt * 16 + mrow;
            if (k0 + 8 <= ATT_IN_C)
                bfr[ks][nt] = *(const bf16x8*)(w1b + (long)n * ATT_IN_C + k0);
            else
                bfr[ks][nt] = bzero8();
        }
    }

    float b1v[9], w2v[9];
#pragma unroll
    for (int nt = 0; nt < 9; ++nt) {
        int n = nt * 16 + mrow;
        b1v[nt] = b1[n];
        w2v[nt] = w2[n];
    }
    float b2v = b2[0];

    bf16x8 acur[6], anext[6];
    int ns = 0, nd = 0;
    {
        long p0 = t0 * 16 + mrow;
        int cs = csr_src[p0], cd = csr_dst[p0];
        load_afrags(cs, cd, t0, mrow, quad, xb, xsb, efp, acur);
        if (t0 + 1 < t1) {
            long p1 = (t0 + 1) * 16 + mrow;
            int s1 = csr_src[p1], d1 = csr_dst[p1];
            load_afrags(s1, d1, t0 + 1, mrow, quad, xb, xsb, efp, anext);
        }
    }

    for (long t = t0; t < t1; ++t) {
        if (t + 2 < t1) {
            long p2 = (t + 2) * 16 + mrow;
            ns = csr_src[p2];
            nd = csr_dst[p2];
        }

        f32x4 acc[9];
#pragma unroll
        for (int nt = 0; nt < 9; ++nt) acc[nt] = (f32x4){0.f, 0.f, 0.f, 0.f};

#pragma unroll
        for (int ks = 0; ks < 6; ++ks) {
#pragma unroll
            for (int nt = 0; nt < 9; ++nt) {
                acc[nt] = __builtin_amdgcn_mfma_f32_16x16x32_bf16(
                    acur[ks], bfr[ks][nt], acc[nt], 0, 0, 0);
            }
        }

        float p0 = 0.f, p1 = 0.f, p2 = 0.f, p3 = 0.f;
#pragma unroll
        for (int nt = 0; nt < 9; ++nt) {
            p0 += w2v[nt] * fmaxf(acc[nt][0] + b1v[nt], 0.f);
            p1 += w2v[nt] * fmaxf(acc[nt][1] + b1v[nt], 0.f);
            p2 += w2v[nt] * fmaxf(acc[nt][2] + b1v[nt], 0.f);
            p3 += w2v[nt] * fmaxf(acc[nt][3] + b1v[nt], 0.f);
        }
#pragma unroll
        for (int off = 1; off < 16; off <<= 1) {
            p0 += __shfl_xor(p0, off, 64);
            p1 += __shfl_xor(p1, off, 64);
            p2 += __shfl_xor(p2, off, 64);
            p3 += __shfl_xor(p3, off, 64);
        }
        if (mrow < 4) {
            float v = (mrow == 0) ? p0 : (mrow == 1) ? p1 : (mrow == 2) ? p2 : p3;
            v += b2v;
            v = (v >= 0.f) ? v : 0.01f * v;
            raw[t * 16 + quad * 4 + mrow] = v;
        }

#pragma unroll
        for (int i = 0; i < 6; ++i) acur[i] = anext[i];
        if (t + 2 < t1)
            load_afrags(ns, nd, t + 2, mrow, quad, xb, xsb, efp, anext);
    }
}

// ---- per-node segment softmax + weighted gather (CSR-sequential raw) -> bf16 agg
__global__ __launch_bounds__(256) void k_agg(
    const __bf16* __restrict__ xb, const int* __restrict__ offsets,
    const int* __restrict__ csr_src,
    const float* __restrict__ raw, __bf16* __restrict__ aggb)
{
    int tid = threadIdx.x;
    int wave = tid >> 6, lane = tid & 63;
    int v = blockIdx.x * 4 + wave;
    if (v >= N_NODES_C) return;
    int s0 = offsets[v], s1 = offsets[v + 1];

    float m = -INFINITY;
    for (int p = s0 + lane; p < s1; p += 64) m = fmaxf(m, raw[p]);
#pragma unroll
    for (int off = 32; off > 0; off >>= 1) m = fmaxf(m, __shfl_xor(m, off, 64));

    float acc = 0.f, sum = 0.f;
    for (int p = s0; p < s1; ++p) {
        int src = csr_src[p];
        float w = expf(raw[p] - m);
        sum += w;
        acc += w * (float)xb[(long)src * 64 + lane];
    }
    aggb[(long)v * 64 + lane] = (__bf16)(acc / (sum + 1e-9f));
}

// ---- node update MLP via bf16 MFMA: one wave = 16 nodes
__global__ __launch_bounds__(256) void k_upd_mfma(
    const __bf16* __restrict__ xb, const __bf16* __restrict__ aggb,
    const __bf16* __restrict__ w1b, const float* __restrict__ b1,
    const __bf16* __restrict__ w2b, const float* __restrict__ b2,
    float* __restrict__ out)
{
    __shared__ __bf16 ubuf[4][16 * 136];   // per-wave 16x128 hidden tile, stride 136
    int tid = threadIdx.x, wid = tid >> 6, lane = tid & 63;
    int tile = blockIdx.x * 4 + wid;
    if (tile >= UPD_TILES) return;
    int mrow = lane & 15, quad = lane >> 4;

    long node = (long)tile * 16 + mrow;
    bf16x8 a1[4];
    a1[0] = *(const bf16x8*)(xb + node * 64 + quad * 8);
    a1[1] = *(const bf16x8*)(xb + node * 64 + 32 + quad * 8);
    a1[2] = *(const bf16x8*)(aggb + node * 64 + quad * 8);
    a1[3] = *(const bf16x8*)(aggb + node * 64 + 32 + quad * 8);

    bf16x8 b1f[4][8];
#pragma unroll
    for (int ks = 0; ks < 4; ++ks)
#pragma unroll
        for (int nt = 0; nt < 8; ++nt)
            b1f[ks][nt] = *(const bf16x8*)(w1b + (long)(nt * 16 + mrow) * 128 + ks * 32 + quad * 8);

    f32x4 acc1[8];
#pragma unroll
    for (int nt = 0; nt < 8; ++nt) acc1[nt] = (f32x4){0.f, 0.f, 0.f, 0.f};
#pragma unroll
    for (int ks = 0; ks < 4; ++ks)
#pragma unroll
        for (int nt = 0; nt < 8; ++nt)
            acc1[nt] = __builtin_amdgcn_mfma_f32_16x16x32_bf16(a1[ks], b1f[ks][nt], acc1[nt], 0, 0, 0);

    __bf16* ub = ubuf[wid];
#pragma unroll
    for (int nt = 0; nt < 8; ++nt) {
        float bb = b1[nt * 16 + mrow];
#pragma unroll
        for (int r = 0; r < 4; ++r) {
            float h = fmaxf(acc1[nt][r] + bb, 0.f);
            ub[(quad * 4 + r) * 136 + nt * 16 + mrow] = (__bf16)h;
        }
    }
    // same-wave ds_write -> ds_read dependency handled via lgkmcnt

    bf16x8 a2[4];
#pragma unroll
    for (int ks = 0; ks < 4; ++ks)
        a2[ks] = *(bf16x8*)&ub[mrow * 136 + ks * 32 + quad * 8];

    bf16x8 b2f[4][4];
#pragma unroll
    for (int ks = 0; ks < 4; ++ks)
#pragma unroll
        for (int nt = 0; nt < 4; ++nt)
            b2f[ks][nt] = *(const bf16x8*)(w2b + (long)(nt * 16 + mrow) * 128 + ks * 32 + quad * 8);

    f32x4 acc2[4];
#pragma unroll
    for (int nt = 0; nt < 4; ++nt) acc2[nt] = (f32x4){0.f, 0.f, 0.f, 0.f};
#pragma unroll
    for (int ks = 0; ks < 4; ++ks)
#pragma unroll
        for (int nt = 0; nt < 4; ++nt)
            acc2[nt] = __builtin_amdgcn_mfma_f32_16x16x32_bf16(a2[ks], b2f[ks][nt], acc2[nt], 0, 0, 0);

#pragma unroll
    for (int nt = 0; nt < 4; ++nt) {
        float bb = b2[nt * 16 + mrow];
#pragma unroll
        for (int r = 0; r < 4; ++r) {
            long nodeo = (long)tile * 16 + quad * 4 + r;
            out[nodeo * 64 + nt * 16 + mrow] = fmaxf(acc2[nt][r] + bb, 0.f);
        }
    }
}

extern "C" void kernel_launch(void* const* d_in, const int* in_sizes, int n_in,
                              void* d_out, int out_size, void* d_ws, size_t ws_size,
                              hipStream_t stream) {
    const float* x    = (const float*)d_in[0];
    const float* xs   = (const float*)d_in[1];
    const int*   ei   = (const int*)d_in[2];
    const float* ef   = (const float*)d_in[3];
    const float* aw1  = (const float*)d_in[4];
    const float* ab1  = (const float*)d_in[5];
    const float* aw2  = (const float*)d_in[6];
    const float* ab2  = (const float*)d_in[7];
    const float* uw1  = (const float*)d_in[8];
    const float* ub1  = (const float*)d_in[9];
    const float* uw2  = (const float*)d_in[10];
    const float* ub2  = (const float*)d_in[11];
    float* out = (float*)d_out;

    char* ws = (char*)d_ws;
    float*  raw     = (float*)(ws + O_RAW);
    int*    deg     = (int*)(ws + O_DEG);
    int*    offsets = (int*)(ws + O_OFF);
    int*    cursor  = (int*)(ws + O_CUR);
    int*    csr_src = (int*)(ws + O_CSRS);
    int*    csr_dst = (int*)(ws + O_CSRD);
    __bf16* efp     = (__bf16*)(ws + O_EFP);
    __bf16* xb      = (__bf16*)(ws + O_XB);
    __bf16* xsb     = (__bf16*)(ws + O_XSB);
    __bf16* w1b     = (__bf16*)(ws + O_W1B);
    __bf16* uw1b    = (__bf16*)(ws + O_UW1B);
    __bf16* uw2b    = (__bf16*)(ws + O_UW2B);
    __bf16* aggb    = (__bf16*)(ws + O_AGGB);
    int*    psum    = (int*)(ws + O_PSUM);
    int*    boff    = (int*)(ws + O_BOFF);

    hipLaunchKernelGGL(k_zero_deg, dim3((N_NODES_C + 255) / 256), dim3(256), 0, stream, deg);
    hipLaunchKernelGGL(k_deg,      dim3((E_C + 255) / 256),       dim3(256), 0, stream, ei, deg);
    hipLaunchKernelGGL(k_scan1,    dim3(SCAN_B),                  dim3(256), 0, stream, deg, psum);
    hipLaunchKernelGGL(k_scan2,    dim3(1),                       dim3(128), 0, stream, psum, boff, offsets);
    hipLaunchKernelGGL(k_scan3,    dim3(SCAN_B),                  dim3(256), 0, stream, deg, boff, offsets, cursor);
    hipLaunchKernelGGL(k_fill,     dim3((E_C + 255) / 256),       dim3(256), 0, stream,
                       ei, ef, cursor, csr_src, csr_dst, efp);
    hipLaunchKernelGGL(k_cvt,      dim3(1978),                    dim3(256), 0, stream,
                       x, xs, aw1, uw1, uw2, xb, xsb, w1b, uw1b, uw2b);
    hipLaunchKernelGGL(k_scores_mfma, dim3(256),                  dim3(256), 0, stream,
                       xb, xsb, efp, w1b, csr_src, csr_dst, ab1, aw2, ab2, raw);
    hipLaunchKernelGGL(k_agg,      dim3((N_NODES_C + 3) / 4),     dim3(256), 0, stream,
                       xb, offsets, csr_src, raw, aggb);
    hipLaunchKernelGGL(k_upd_mfma, dim3((UPD_TILES + 3) / 4),     dim3(256), 0, stream,
                       xb, aggb, uw1b, ub1, uw2b, ub2, out);
}